// Round 16
// baseline (410.394 us; speedup 1.0000x reference)
//
#include <hip/hip_runtime.h>
#include <math.h>

#define WID 1024
#define HEI 1024
#define OUTC 112     // output cols per wave (2 cols/lane, 8-col halo each side)
#define BH 16        // output rows per wave
#define CB 10        // col bands: 9*112 + 16 = 1024
#define RB 64        // row bands: 8 XCD stripes * 8 bands

__device__ __forceinline__ float lane_up1(float v) {   // lane i <- lane i-1
    return __int_as_float(__builtin_amdgcn_update_dpp(
        __float_as_int(v), __float_as_int(v), 0x138, 0xF, 0xF, false)); // wave_shr:1
}
__device__ __forceinline__ float lane_dn1(float v) {   // lane i <- lane i+1
    return __int_as_float(__builtin_amdgcn_update_dpp(
        __float_as_int(v), __float_as_int(v), 0x130, 0xF, 0xF, false)); // wave_shl:1
}
__device__ __forceinline__ float fmin3(float a, float b, float c) {
    float d; asm("v_min3_f32 %0, %1, %2, %3" : "=v"(d) : "v"(a), "v"(b), "v"(c));
    return d;
}
__device__ __forceinline__ float fmax3(float a, float b, float c) {
    float d; asm("v_max3_f32 %0, %1, %2, %3" : "=v"(d) : "v"(a), "v"(b), "v"(c));
    return d;
}

// 4-rows-per-step fused pipeline, 2 columns per lane (float2).
// Structure identical to r12/r15 (verified absmax=0); only the column packing changed.
template<int K, bool FIRST, bool WIMG, bool EDGE>
__device__ __forceinline__ void body4(const float* __restrict__ imgp,
                                      float* __restrict__ outi,
                                      float* __restrict__ outs,
                                      int r0, int x, int xc, bool colIn, bool outLane)
{
    constexpr int FILL  = ((K & 3) == 3) ? (K + 6) : (K + 8);  // 13 (K=7), 14 (K=6)
    constexpr int NSTEP = (BH + 20) / 4;                        // 9
    const float INF = INFINITY;

    float2 c[K+1], d[K+1], sk[16];
    #pragma unroll
    for (int j = 0; j <= K; ++j) { c[j] = make_float2(INF, INF); d[j] = make_float2(INF, INF); }
    #pragma unroll
    for (int t = 0; t < 16; ++t) sk[t] = make_float2(0.f, 0.f);

    float2 vI[4], vS[4];
    #pragma unroll
    for (int q = 0; q < 4; ++q) vS[q] = make_float2(0.f, 0.f);

    // prime img loads: rows for step 1 (rr = 1-FILL+q)
    #pragma unroll
    for (int q = 0; q < 4; ++q) {
        const int rr = 1 - FILL + q;
        if (EDGE) {
            int row = r0 + rr;
            bool rin = (unsigned)row < (unsigned)HEI;
            int rowc = row < 0 ? 0 : (row > HEI-1 ? HEI-1 : row);
            float2 v = *(const float2*)&imgp[(size_t)rowc * WID + xc];
            bool ok = rin && colIn;
            vI[q] = make_float2(ok ? v.x : INF, ok ? v.y : INF);
        } else {
            vI[q] = *(const float2*)&imgp[(size_t)(r0 + rr) * WID + x];
        }
    }

    #pragma unroll
    for (int n = 1; n <= NSTEP; ++n) {
        // ---- stage-0 buffer: rows 4n-FILL-5 .. 4n-FILL ----
        float2 bp[6] = { c[0], d[0], vI[0], vI[1], vI[2], vI[3] };
        c[0] = bp[4]; d[0] = bp[5];

        // ---- entering skel rows ----
        #pragma unroll
        for (int q = 0; q < 4; ++q) {
            const int rrE = 4*n - FILL - 5 + q;
            if (rrE >= 0 && rrE < BH) sk[rrE & 15] = FIRST ? make_float2(0.f, 0.f) : vS[q];
        }

        // ---- prefetch loads for step n+1 ----
        if (n < NSTEP) {
            #pragma unroll
            for (int q = 0; q < 4; ++q) {
                const int rr = 4*(n+1) - FILL - 3 + q;
                if (EDGE) {
                    int row = r0 + rr;
                    bool rin = (unsigned)row < (unsigned)HEI;
                    int rowc = row < 0 ? 0 : (row > HEI-1 ? HEI-1 : row);
                    float2 v = *(const float2*)&imgp[(size_t)rowc * WID + xc];
                    bool ok = rin && colIn;
                    vI[q] = make_float2(ok ? v.x : INF, ok ? v.y : INF);
                } else {
                    vI[q] = *(const float2*)&imgp[(size_t)(r0 + rr) * WID + x];
                }
            }
            if (!FIRST) {
                #pragma unroll
                for (int q = 0; q < 4; ++q) {
                    const int rrL = 4*(n+1) - FILL - 5 + q;
                    if (rrL >= 0 && rrL < BH)
                        vS[q] = EDGE ? *(const float2*)&outs[(size_t)(r0 + rrL) * WID + xc]
                                     : *(const float2*)&outs[(size_t)(r0 + rrL) * WID + x];
                }
            }
        }

        float2 eK[6];

        // ---- stages j=1..K, each followed by op t=j-1 ----
        #pragma unroll
        for (int j = 1; j <= K; ++j) {
            float2 o[4];
            #pragma unroll
            for (int q = 0; q < 4; ++q) {
                float2 up = bp[q], ce = bp[q+1], dn = bp[q+2];
                float vx = fmin3(up.x, ce.x, dn.x);
                float vy = fmin3(up.y, ce.y, dn.y);
                float lf = lane_up1(ce.y);     // col left of ce.x
                float rt = lane_dn1(ce.x);     // col right of ce.y
                float njx = fmin3(vx, lf, ce.y);
                float njy = fmin3(vy, ce.x, rt);
                if (EDGE) {
                    const int rr = 4*n - FILL - 3 - j + q;
                    bool ok = ((unsigned)(r0 + rr) < (unsigned)HEI) && colIn;
                    njx = ok ? njx : INF;
                    njy = ok ? njy : INF;
                }
                o[q] = make_float2(njx, njy);
            }
            float2 bc[6] = { c[j], d[j], o[0], o[1], o[2], o[3] };
            c[j] = bc[4]; d[j] = bc[5];

            // op t = j-1: output rows rr = 4n-FILL-5-t+q; e1 = bp[q]; dilate over bc
            {
                const int t = j - 1;
                #pragma unroll
                for (int q = 0; q < 4; ++q) {
                    const int rr = 4*n - FILL - 5 - t + q;
                    float2 a0 = bc[q], a1 = bc[q+1], a2 = bc[q+2];
                    if (EDGE) {
                        bool i0 = (unsigned)(r0 + rr - 1) < (unsigned)HEI;
                        bool i1 = (unsigned)(r0 + rr    ) < (unsigned)HEI;
                        bool i2 = (unsigned)(r0 + rr + 1) < (unsigned)HEI;
                        a0 = make_float2(i0 ? a0.x : -INF, i0 ? a0.y : -INF);
                        a1 = make_float2(i1 ? a1.x : -INF, i1 ? a1.y : -INF);
                        a2 = make_float2(i2 ? a2.x : -INF, i2 ? a2.y : -INF);
                    }
                    float vmx = fmax3(a0.x, a1.x, a2.x);
                    float vmy = fmax3(a0.y, a1.y, a2.y);
                    if (EDGE) {
                        vmx = colIn ? vmx : -INF;
                        vmy = colIn ? vmy : -INF;
                    }
                    float hl = lane_up1(vmy);
                    float hr = lane_dn1(vmx);
                    float ddx = fmax3(vmx, hl, vmy);
                    float ddy = fmax3(vmy, vmx, hr);
                    float dex = fmaxf(bp[q].x - ddx, 0.f);
                    float dey = fmaxf(bp[q].y - ddy, 0.f);
                    float2 sv = sk[rr & 15];
                    sk[rr & 15] = make_float2(sv.x + fmaf(-sv.x, dex, dex),
                                              sv.y + fmaf(-sv.y, dey, dey));
                }
            }
            #pragma unroll
            for (int p = 0; p < 6; ++p) bp[p] = bc[p];
            if (j == K) {
                #pragma unroll
                for (int p = 0; p < 6; ++p) eK[p] = bc[p];
            }
        }

        // ---- stores: rows 4n-24+q (skel final; E^K = eK[1+q]) ----
        #pragma unroll
        for (int q = 0; q < 4; ++q) {
            const int rr = 4*n - 24 + q;
            if (rr >= 0 && rr < BH) {
                if (outLane) {
                    *(float2*)&outs[(size_t)(r0 + rr) * WID + x] = sk[rr & 15];
                    if (WIMG) *(float2*)&outi[(size_t)(r0 + rr) * WID + x] = eK[1 + q];
                }
            }
        }
    }
}

template<int K, bool FIRST, bool WIMG>
__global__ __launch_bounds__(256, 3)
void pass_kernel(const float* __restrict__ img_in, float* __restrict__ img_out,
                 float* __restrict__ skel)
{
    const int lane = threadIdx.x & 63;
    const int warp = threadIdx.x >> 6;
    // XCD swizzle: rbg = bid&7 -> XCD; each XCD owns a contiguous 128-row stripe
    // (8 bands of 16 rows); 2 blocks (sub) per stripe per col-band.
    const int bid   = blockIdx.x;
    const int rbg   = bid & 7;
    const int rest  = bid >> 3;
    const int sub   = rest & 1;
    const int rest2 = rest >> 1;
    const int cb    = rest2 % CB;
    const int b     = rest2 / CB;
    const int rb    = rbg*8 + sub*4 + warp;   // 0..63

    const int outc = (cb == CB-1) ? (WID - (CB-1)*OUTC) : OUTC;  // 112 or 16
    const int x0   = cb*OUTC - 8;            // 8-col halo
    const int x    = x0 + 2*lane;            // even
    const int xc   = x < 0 ? 0 : (x > WID-2 ? WID-2 : x);
    const bool colIn   = ((unsigned)x < (unsigned)WID);          // valid for both cols
    const bool outLane = (lane >= 4) && (lane < 4 + outc/2);
    const int r0   = rb*BH;
    const size_t base = (size_t)b*HEI*WID;

    const float* imgp = img_in + base;
    float* outi = WIMG ? (img_out + base) : nullptr;
    float* outs = skel + base;

    const bool edge = (cb == 0) || (cb == CB-1) || (rb == 0) || (rb == RB-1);
    if (edge)
        body4<K, FIRST, WIMG, true >(imgp, outi, outs, r0, x, xc, colIn, outLane);
    else
        body4<K, FIRST, WIMG, false>(imgp, outi, outs, r0, x, xc, colIn, outLane);
}

extern "C" void kernel_launch(void* const* d_in, const int* in_sizes, int n_in,
                              void* d_out, int out_size, void* d_ws, size_t ws_size,
                              hipStream_t stream)
{
    const float* img = (const float*)d_in[0];
    float* skel = (float*)d_out;
    const int total = in_sizes[0];
    const int B = total / (HEI*WID);

    float* bufA = (float*)d_ws;
    float* bufB = bufA + (size_t)total;

    const int blocks = 8 * 2 * CB * B;   // 4 row-band waves per block

    // 41 ops (t=0..40): 5 passes of K=7, then K=6.
    pass_kernel<7,true, true ><<<blocks,256,0,stream>>>(img,  bufA, skel); // t=0..6
    pass_kernel<7,false,true ><<<blocks,256,0,stream>>>(bufA, bufB, skel); // t=7..13
    pass_kernel<7,false,true ><<<blocks,256,0,stream>>>(bufB, bufA, skel); // t=14..20
    pass_kernel<7,false,true ><<<blocks,256,0,stream>>>(bufA, bufB, skel); // t=21..27
    pass_kernel<7,false,true ><<<blocks,256,0,stream>>>(bufB, bufA, skel); // t=28..34
    pass_kernel<6,false,false><<<blocks,256,0,stream>>>(bufA, nullptr, skel); // t=35..40
}

// Round 17
// 365.217 us; speedup vs baseline: 1.1237x; 1.1237x over previous
//
#include <hip/hip_runtime.h>
#include <math.h>

#define WID 1024
#define HEI 1024
#define OUTC 48      // output cols per wave
#define HALOC 8      // halo lanes each side (supports K<=7)
#define BH 32        // output rows per wave
#define CB 22        // col bands: 21*48 + 16 = 1024
#define RB 32        // row bands: 8 XCD stripes * 4 warps

__device__ __forceinline__ float lane_up1(float v) {   // lane i <- lane i-1
    return __int_as_float(__builtin_amdgcn_update_dpp(
        __float_as_int(v), __float_as_int(v), 0x138, 0xF, 0xF, false)); // wave_shr:1
}
__device__ __forceinline__ float lane_dn1(float v) {   // lane i <- lane i+1
    return __int_as_float(__builtin_amdgcn_update_dpp(
        __float_as_int(v), __float_as_int(v), 0x130, 0xF, 0xF, false)); // wave_shl:1
}
__device__ __forceinline__ float fmin3(float a, float b, float c) {
    float d; asm("v_min3_f32 %0, %1, %2, %3" : "=v"(d) : "v"(a), "v"(b), "v"(c));
    return d;
}
__device__ __forceinline__ float fmax3(float a, float b, float c) {
    float d; asm("v_max3_f32 %0, %1, %2, %3" : "=v"(d) : "v"(a), "v"(b), "v"(c));
    return d;
}

// 8-rows-per-step fused pipeline (r13 schedule, correctness-verified there).
// Straight-line: 6 explicit step expansions — no outer loop for LLVM to
// decline unrolling; every array index is a compile-time constant.
// F >= K+2 (cone tightness), F == -K (mod 8) (store alignment); NS0*8 = F+K+8.

#define SSTEP(n)                                                               \
  {                                                                            \
    float bp[10] = { c[0], d[0], vI[0], vI[1], vI[2], vI[3],                   \
                     vI[4], vI[5], vI[6], vI[7] };                             \
    c[0] = bp[8]; d[0] = bp[9];                                                \
    _Pragma("unroll")                                                          \
    for (int q = 0; q < 8; ++q) {                                              \
      const int rrE = 8*(n) - F - 9 + q;                                       \
      if (rrE >= 0 && rrE < BH) sk[rrE & 15] = FIRST ? 0.f : vS[q];            \
    }                                                                          \
    if ((n) < NSTEP) {                                                         \
      _Pragma("unroll")                                                        \
      for (int q = 0; q < 8; ++q) {                                            \
        const int rr = 8*((n)+1) - F - 7 + q;                                  \
        if (EDGE) {                                                            \
          int row = r0 + rr;                                                   \
          bool rin = (unsigned)row < (unsigned)HEI;                            \
          int rowc = row < 0 ? 0 : (row > HEI-1 ? HEI-1 : row);                \
          float v = imgp[(size_t)rowc * WID + xc];                             \
          vI[q] = (rin && colIn) ? v : INFINITY;                               \
        } else {                                                               \
          vI[q] = imgp[(size_t)(r0 + rr) * WID + x];                           \
        }                                                                      \
      }                                                                        \
      if (!FIRST) {                                                            \
        _Pragma("unroll")                                                      \
        for (int q = 0; q < 8; ++q) {                                          \
          const int rrL = 8*((n)+1) - F - 9 + q;                               \
          if (rrL >= 0 && rrL < BH)                                            \
            vS[q] = EDGE ? outs[(size_t)(r0 + rrL) * WID + xc]                 \
                         : outs[(size_t)(r0 + rrL) * WID + x];                 \
        }                                                                      \
      }                                                                        \
    }                                                                          \
    _Pragma("unroll")                                                          \
    for (int j = 1; j <= K; ++j) {                                             \
      float bc[10];                                                            \
      bc[0] = c[j]; bc[1] = d[j];                                              \
      _Pragma("unroll")                                                        \
      for (int q = 0; q < 8; ++q) {                                            \
        float up = bp[q], ce = bp[q+1], dn = bp[q+2];                          \
        float lf = lane_up1(ce), rt = lane_dn1(ce);                            \
        float pre = fmin3(up, ce, lf);                                         \
        float nj  = fmin3(pre, rt, dn);                                        \
        if (EDGE) {                                                            \
          const int rr = 8*(n) - F - 7 - j + q;                                \
          bool rin = (unsigned)(r0 + rr) < (unsigned)HEI;                      \
          nj = (rin && colIn) ? nj : INFINITY;                                 \
        }                                                                      \
        bc[2+q] = nj;                                                          \
      }                                                                        \
      c[j] = bc[8]; d[j] = bc[9];                                              \
      {                                                                        \
        const int t = j - 1;                                                   \
        _Pragma("unroll")                                                      \
        for (int q = 0; q < 8; ++q) {                                          \
          const int rr = 8*(n) - F - 9 - t + q;                                \
          float a0 = bc[q], a1 = bc[q+1], a2 = bc[q+2];                        \
          if (EDGE) {                                                          \
            bool i0 = (unsigned)(r0 + rr - 1) < (unsigned)HEI;                 \
            bool i1 = (unsigned)(r0 + rr    ) < (unsigned)HEI;                 \
            bool i2 = (unsigned)(r0 + rr + 1) < (unsigned)HEI;                 \
            a0 = i0 ? a0 : -INFINITY;                                          \
            a1 = i1 ? a1 : -INFINITY;                                          \
            a2 = i2 ? a2 : -INFINITY;                                          \
          }                                                                    \
          float vm = fmax3(a0, a1, a2);                                        \
          if (EDGE) vm = colIn ? vm : -INFINITY;                               \
          float hl = lane_up1(vm), hr = lane_dn1(vm);                          \
          float dd = fmax3(hl, hr, vm);                                        \
          float delta = fmaxf(bp[q] - dd, 0.f);                                \
          float sv = sk[rr & 15];                                              \
          sk[rr & 15] = sv + fmaf(-sv, delta, delta);                          \
        }                                                                      \
      }                                                                        \
      if (j < K) {                                                             \
        _Pragma("unroll")                                                      \
        for (int p = 0; p < 10; ++p) bp[p] = bc[p];                            \
      } else if ((n) >= NS0) {                                                 \
        _Pragma("unroll")                                                      \
        for (int q = 0; q < 8; ++q) {                                          \
          const int rr = 8*(n) - 8*NS0 + q;                                    \
          if (outLane) {                                                       \
            outs[(size_t)(r0 + rr) * WID + x] = sk[rr & 15];                   \
            if (WIMG) outi[(size_t)(r0 + rr) * WID + x] = bc[q + 1];           \
          }                                                                    \
        }                                                                      \
      }                                                                        \
    }                                                                          \
  }

template<int K, bool FIRST, bool WIMG, bool EDGE>
__device__ __forceinline__ void body8(const float* __restrict__ imgp,
                                      float* __restrict__ outi,
                                      float* __restrict__ outs,
                                      int r0, int x, int xc, bool colIn, bool outLane)
{
    constexpr int F     = K + 2 + ((14 - 2*K) % 8 + 8) % 8;  // 9 (K=7), 10 (K=6)
    constexpr int NS0   = (F + K + 8) / 8;                   // 3
    constexpr int NSTEP = (F + K + 32) / 8;                  // 6

    float c[K+1], d[K+1], sk[16];
    #pragma unroll
    for (int j = 0; j <= K; ++j) { c[j] = INFINITY; d[j] = INFINITY; }
    #pragma unroll
    for (int t = 0; t < 16; ++t) sk[t] = 0.f;

    float vI[8], vS[8] = {0.f,0.f,0.f,0.f,0.f,0.f,0.f,0.f};

    // prime img loads: rows consumed at step 1 (rr = 1-F+q)
    #pragma unroll
    for (int q = 0; q < 8; ++q) {
        const int rr = 1 - F + q;
        if (EDGE) {
            int row = r0 + rr;
            bool rin = (unsigned)row < (unsigned)HEI;
            int rowc = row < 0 ? 0 : (row > HEI-1 ? HEI-1 : row);
            float v = imgp[(size_t)rowc * WID + xc];
            vI[q] = (rin && colIn) ? v : INFINITY;
        } else {
            vI[q] = imgp[(size_t)(r0 + rr) * WID + x];
        }
    }

    SSTEP(1)
    SSTEP(2)
    SSTEP(3)
    SSTEP(4)
    SSTEP(5)
    SSTEP(6)
}

template<int K, bool FIRST, bool WIMG>
__global__ __launch_bounds__(256, 3)
void pass_kernel(const float* __restrict__ img_in, float* __restrict__ img_out,
                 float* __restrict__ skel)
{
    const int lane = threadIdx.x & 63;
    const int warp = threadIdx.x >> 6;
    // XCD swizzle: rbg = bid&7 -> XCD; each XCD owns a contiguous 128-row stripe.
    const int bid  = blockIdx.x;
    const int rbg  = bid & 7;
    const int rest = bid >> 3;
    const int cb   = rest % CB;
    const int b    = rest / CB;
    const int rb   = rbg*4 + warp;   // 0..31

    const int outc = (cb == CB-1) ? (WID - (CB-1)*OUTC) : OUTC;  // 48 or 16
    const int x0   = cb*OUTC - HALOC;
    const int r0   = rb*BH;
    const int x    = x0 + lane;
    const int xc   = x < 0 ? 0 : (x > WID-1 ? WID-1 : x);
    const bool colIn   = ((unsigned)x < (unsigned)WID);
    const bool outLane = (lane >= HALOC) && (lane < HALOC + outc);
    const size_t base = (size_t)b*HEI*WID;

    const float* imgp = img_in + base;
    float* outi = WIMG ? (img_out + base) : nullptr;
    float* outs = skel + base;

    const bool edge = (cb == 0) || (cb == CB-1) || (rb == 0) || (rb == RB-1);
    if (edge)
        body8<K, FIRST, WIMG, true >(imgp, outi, outs, r0, x, xc, colIn, outLane);
    else
        body8<K, FIRST, WIMG, false>(imgp, outi, outs, r0, x, xc, colIn, outLane);
}

extern "C" void kernel_launch(void* const* d_in, const int* in_sizes, int n_in,
                              void* d_out, int out_size, void* d_ws, size_t ws_size,
                              hipStream_t stream)
{
    const float* img = (const float*)d_in[0];
    float* skel = (float*)d_out;
    const int total = in_sizes[0];
    const int B = total / (HEI*WID);

    float* bufA = (float*)d_ws;
    float* bufB = bufA + (size_t)total;

    const int blocks = 8 * CB * B;   // 4 row-band waves per block

    // 41 ops (t=0..40): 5 passes of K=7, then K=6.
    pass_kernel<7,true, true ><<<blocks,256,0,stream>>>(img,  bufA, skel); // t=0..6
    pass_kernel<7,false,true ><<<blocks,256,0,stream>>>(bufA, bufB, skel); // t=7..13
    pass_kernel<7,false,true ><<<blocks,256,0,stream>>>(bufB, bufA, skel); // t=14..20
    pass_kernel<7,false,true ><<<blocks,256,0,stream>>>(bufA, bufB, skel); // t=21..27
    pass_kernel<7,false,true ><<<blocks,256,0,stream>>>(bufB, bufA, skel); // t=28..34
    pass_kernel<6,false,false><<<blocks,256,0,stream>>>(bufA, nullptr, skel); // t=35..40
}

// Round 18
// 187.067 us; speedup vs baseline: 2.1938x; 1.9523x over previous
//
#include <hip/hip_runtime.h>
#include <math.h>

#define WID 1024
#define HEI 1024
#define OUTC 48      // output cols per wave
#define HALOC 8      // halo lanes each side (supports K<=7)
#define BH 16        // output rows per wave
#define CB 22        // col bands: 21*48 + 16 = 1024
#define RB 64        // row bands: 8 XCD stripes * 8 bands
#define IMG_ROWS 37  // staged img rows: rr in [-13, 23]
#define ROFF 13      // row offset into LDS img buffer

__device__ __forceinline__ float lane_up1(float v) {   // lane i <- lane i-1
    return __int_as_float(__builtin_amdgcn_update_dpp(
        __float_as_int(v), __float_as_int(v), 0x138, 0xF, 0xF, false)); // wave_shr:1
}
__device__ __forceinline__ float lane_dn1(float v) {   // lane i <- lane i+1
    return __int_as_float(__builtin_amdgcn_update_dpp(
        __float_as_int(v), __float_as_int(v), 0x130, 0xF, 0xF, false)); // wave_shl:1
}
__device__ __forceinline__ float fmin3(float a, float b, float c) {
    float d; asm("v_min3_f32 %0, %1, %2, %3" : "=v"(d) : "v"(a), "v"(b), "v"(c));
    return d;
}
__device__ __forceinline__ float fmax3(float a, float b, float c) {
    float d; asm("v_max3_f32 %0, %1, %2, %3" : "=v"(d) : "v"(a), "v"(b), "v"(c));
    return d;
}

// stage NB img rows starting at staged index B0 (row rr = B0+j-ROFF):
// batch loads into temps (>=NB in flight), then ds_write. Wave-private LDS.
#define STAGE_IMG(B0, NB)                                                      \
  {                                                                            \
    float t[NB];                                                               \
    _Pragma("unroll")                                                          \
    for (int j = 0; j < NB; ++j) {                                             \
      const int rr = (B0) + j - ROFF;                                          \
      if (EDGE) {                                                              \
        int row = r0 + rr;                                                     \
        int rowc = row < 0 ? 0 : (row > HEI-1 ? HEI-1 : row);                  \
        t[j] = imgp[(size_t)rowc * WID + xc];                                  \
      } else {                                                                 \
        t[j] = imgp[(size_t)(r0 + rr) * WID + x];                              \
      }                                                                        \
    }                                                                          \
    _Pragma("unroll")                                                          \
    for (int j = 0; j < NB; ++j) li[((B0) + j) * 64 + lane] = t[j];            \
  }

#define STAGE_SK(B0)                                                           \
  {                                                                            \
    float t[8];                                                                \
    _Pragma("unroll")                                                          \
    for (int j = 0; j < 8; ++j)                                                \
      t[j] = EDGE ? outs[(size_t)(r0 + (B0) + j) * WID + xc]                   \
                  : outs[(size_t)(r0 + (B0) + j) * WID + x];                   \
    _Pragma("unroll")                                                          \
    for (int j = 0; j < 8; ++j) ls[((B0) + j) * 64 + lane] = t[j];             \
  }

// 4-rows-per-step fused pipeline (r12/r15 verified structure), LDS-staged input:
// all global loads issue upfront (batched, high MLP), compute reads LDS only.
template<int K, bool FIRST, bool WIMG, bool EDGE>
__device__ __forceinline__ void body4(const float* __restrict__ imgp,
                                      float* __restrict__ outi,
                                      float* __restrict__ outs,
                                      int r0, int x, int xc, bool colIn, bool outLane,
                                      float* li, float* ls, int lane)
{
    constexpr int FILL  = ((K & 3) == 3) ? (K + 6) : (K + 8);  // 13 (K=7), 14 (K=6)
    constexpr int NSTEP = (BH + 20) / 4;                        // 9
    const float INF = INFINITY;

    // ---- staging: all rows -> wave-private LDS (no barriers) ----
    STAGE_IMG(0, 8) STAGE_IMG(8, 8) STAGE_IMG(16, 8) STAGE_IMG(24, 8) STAGE_IMG(32, 5)
    if (!FIRST) { STAGE_SK(0) STAGE_SK(8) }

    float c[K+1], d[K+1], sk[16];
    #pragma unroll
    for (int j = 0; j <= K; ++j) { c[j] = INF; d[j] = INF; }
    #pragma unroll
    for (int t = 0; t < 16; ++t) sk[t] = 0.f;

    #pragma unroll
    for (int n = 1; n <= NSTEP; ++n) {
        // ---- stage-0 input rows from LDS: rr = 4n-FILL-3+q ----
        float vI[4];
        #pragma unroll
        for (int q = 0; q < 4; ++q) {
            const int rr = 4*n - FILL - 3 + q;
            float v = li[(rr + ROFF) * 64 + lane];
            if (EDGE) {
                bool ok = ((unsigned)(r0 + rr) < (unsigned)HEI) && colIn;
                v = ok ? v : INF;
            }
            vI[q] = v;
        }
        float bp[6] = { c[0], d[0], vI[0], vI[1], vI[2], vI[3] };
        c[0] = bp[4]; d[0] = bp[5];

        // ---- entering skel rows (op-0 window this step) ----
        #pragma unroll
        for (int q = 0; q < 4; ++q) {
            const int rrE = 4*n - FILL - 5 + q;
            if (rrE >= 0 && rrE < BH)
                sk[rrE & 15] = FIRST ? 0.f : ls[rrE * 64 + lane];
        }

        float eK[6];

        // ---- stages j=1..K, each followed by op t=j-1 ----
        #pragma unroll
        for (int j = 1; j <= K; ++j) {
            float o[4];
            #pragma unroll
            for (int q = 0; q < 4; ++q) {
                float up = bp[q], ce = bp[q+1], dn = bp[q+2];
                float lf = lane_up1(ce), rt = lane_dn1(ce);
                float pre = fmin3(up, ce, lf);
                float nj  = fmin3(pre, rt, dn);
                if (EDGE) {
                    const int rr = 4*n - FILL - 3 - j + q;
                    bool rin = (unsigned)(r0 + rr) < (unsigned)HEI;
                    nj = (rin && colIn) ? nj : INF;
                }
                o[q] = nj;
            }
            float bc[6] = { c[j], d[j], o[0], o[1], o[2], o[3] };
            c[j] = bc[4]; d[j] = bc[5];

            // op t = j-1: output rows rr = 4n-FILL-5-t+q, e1 = bp[q], dilate over bc
            {
                const int t = j - 1;
                #pragma unroll
                for (int q = 0; q < 4; ++q) {
                    const int rr = 4*n - FILL - 5 - t + q;
                    float a0 = bc[q], a1 = bc[q+1], a2 = bc[q+2];
                    if (EDGE) {
                        bool i0 = (unsigned)(r0 + rr - 1) < (unsigned)HEI;
                        bool i1 = (unsigned)(r0 + rr    ) < (unsigned)HEI;
                        bool i2 = (unsigned)(r0 + rr + 1) < (unsigned)HEI;
                        a0 = i0 ? a0 : -INF;
                        a1 = i1 ? a1 : -INF;
                        a2 = i2 ? a2 : -INF;
                    }
                    float vm = fmax3(a0, a1, a2);
                    if (EDGE) vm = colIn ? vm : -INF;
                    float hl = lane_up1(vm), hr = lane_dn1(vm);
                    float dd = fmax3(hl, hr, vm);
                    float delta = fmaxf(bp[q] - dd, 0.f);
                    float sv = sk[rr & 15];
                    sk[rr & 15] = sv + fmaf(-sv, delta, delta);
                }
            }
            #pragma unroll
            for (int p = 0; p < 6; ++p) bp[p] = bc[p];
            if (j == K) {
                #pragma unroll
                for (int p = 0; p < 6; ++p) eK[p] = bc[p];
            }
        }

        // ---- stores: rows 4n-24+q (skel final after op K-1; E^K = eK[1+q]) ----
        #pragma unroll
        for (int q = 0; q < 4; ++q) {
            const int rr = 4*n - 24 + q;
            if (rr >= 0 && rr < BH) {
                if (outLane) outs[(size_t)(r0 + rr) * WID + x] = sk[rr & 15];
                if (WIMG) { if (outLane) outi[(size_t)(r0 + rr) * WID + x] = eK[1 + q]; }
            }
        }
    }
}

template<int K, bool FIRST, bool WIMG>
__global__ __launch_bounds__(256, 3)
void pass_kernel(const float* __restrict__ img_in, float* __restrict__ img_out,
                 float* __restrict__ skel)
{
    __shared__ float ldsI[4][IMG_ROWS][64];   // 37,888 B
    __shared__ float ldsS[4][BH][64];         // 16,384 B  (total 53 KiB/block)

    const int lane = threadIdx.x & 63;
    const int warp = threadIdx.x >> 6;
    // XCD swizzle: rbg = bid&7 -> XCD; each XCD owns a contiguous 128-row stripe
    // (8 bands of 16 rows); 2 blocks (sub) per stripe per col-band.
    const int bid   = blockIdx.x;
    const int rbg   = bid & 7;
    const int rest  = bid >> 3;
    const int sub   = rest & 1;
    const int rest2 = rest >> 1;
    const int cb    = rest2 % CB;
    const int b     = rest2 / CB;
    const int rb    = rbg*8 + sub*4 + warp;   // 0..63

    const int outc = (cb == CB-1) ? (WID - (CB-1)*OUTC) : OUTC;  // 48 or 16
    const int x0   = cb*OUTC - HALOC;
    const int r0   = rb*BH;
    const int x    = x0 + lane;
    const int xc   = x < 0 ? 0 : (x > WID-1 ? WID-1 : x);
    const bool colIn   = ((unsigned)x < (unsigned)WID);
    const bool outLane = (lane >= HALOC) && (lane < HALOC + outc);
    const size_t base = (size_t)b*HEI*WID;

    const float* imgp = img_in + base;
    float* outi = WIMG ? (img_out + base) : nullptr;
    float* outs = skel + base;
    float* li = &ldsI[warp][0][0];
    float* ls = &ldsS[warp][0][0];

    const bool edge = (cb == 0) || (cb == CB-1) || (rb == 0) || (rb == RB-1);
    if (edge)
        body4<K, FIRST, WIMG, true >(imgp, outi, outs, r0, x, xc, colIn, outLane, li, ls, lane);
    else
        body4<K, FIRST, WIMG, false>(imgp, outi, outs, r0, x, xc, colIn, outLane, li, ls, lane);
}

extern "C" void kernel_launch(void* const* d_in, const int* in_sizes, int n_in,
                              void* d_out, int out_size, void* d_ws, size_t ws_size,
                              hipStream_t stream)
{
    const float* img = (const float*)d_in[0];
    float* skel = (float*)d_out;
    const int total = in_sizes[0];
    const int B = total / (HEI*WID);

    float* bufA = (float*)d_ws;
    float* bufB = bufA + (size_t)total;

    const int blocks = 8 * 2 * CB * B;   // 4 row-band waves per block

    // 41 ops (t=0..40): 5 passes of K=7, then K=6.
    pass_kernel<7,true, true ><<<blocks,256,0,stream>>>(img,  bufA, skel); // t=0..6
    pass_kernel<7,false,true ><<<blocks,256,0,stream>>>(bufA, bufB, skel); // t=7..13
    pass_kernel<7,false,true ><<<blocks,256,0,stream>>>(bufB, bufA, skel); // t=14..20
    pass_kernel<7,false,true ><<<blocks,256,0,stream>>>(bufA, bufB, skel); // t=21..27
    pass_kernel<7,false,true ><<<blocks,256,0,stream>>>(bufB, bufA, skel); // t=28..34
    pass_kernel<6,false,false><<<blocks,256,0,stream>>>(bufA, nullptr, skel); // t=35..40
}